// Round 7
// baseline (295.933 us; speedup 1.0000x reference)
//
#include <hip/hip_runtime.h>
#include <hip/hip_bf16.h>
#include <stdint.h>

#define D 300
#define KP 320   // K padded to 10*32 (MFMA k-loop extent)
#define XP 304   // xb row stride (bf16), 16B-aligned; k>=300 handled by zero W cols
#define JP 304   // out-col padded to 19*16; also zb row stride
#define NT 19    // col tiles (16 wide) per wave

typedef __hip_bfloat16 bf16;
typedef __bf16 bf16x8 __attribute__((ext_vector_type(8)));
typedef unsigned short us8 __attribute__((ext_vector_type(8)));
typedef float f32x4 __attribute__((ext_vector_type(4)));

static __device__ __forceinline__ unsigned short f2bu(float f) {
    bf16 h = __float2bfloat16(f);
    return *reinterpret_cast<unsigned short*>(&h);
}
static __device__ __forceinline__ float bulo(unsigned int u) {
    return __uint_as_float(u << 16);
}
static __device__ __forceinline__ float buhi(unsigned int u) {
    return __uint_as_float(u & 0xffff0000u);
}
static __device__ __forceinline__ void gload_lds16(const void* g, void* l) {
    __builtin_amdgcn_global_load_lds(
        (const __attribute__((address_space(1))) unsigned int*)g,
        (__attribute__((address_space(3))) unsigned int*)l, 16, 0, 0);
}

// ---------------- count in-degree (deg pre-zeroed by memset) ----------------
__global__ void k_count(const int* __restrict__ col, int* __restrict__ deg, int e) {
    int i = blockIdx.x * 256 + threadIdx.x;
    if (i < e) atomicAdd(&deg[col[i]], 1);
}

// ------- exclusive scan of deg (=in-degree) + fused dinv = rsqrt(deg+1) -------
__global__ void k_scanA(const int* __restrict__ deg, int* __restrict__ ex,
                        float* __restrict__ dinv, int* __restrict__ bsum, int n) {
    __shared__ int sh[256];
    int tid = threadIdx.x;
    int base = blockIdx.x * 1024 + tid * 4;
    int v[4]; int s = 0;
#pragma unroll
    for (int t = 0; t < 4; t++) {
        int i = base + t;
        v[t] = (i < n) ? deg[i] : 0;
        if (i < n) dinv[i] = rsqrtf((float)(v[t] + 1));   // +1 = self loop
        s += v[t];
    }
    sh[tid] = s;
    __syncthreads();
    for (int off = 1; off < 256; off <<= 1) {
        int t = (tid >= off) ? sh[tid - off] : 0;
        __syncthreads();
        sh[tid] += t;
        __syncthreads();
    }
    int excl = sh[tid] - s;
#pragma unroll
    for (int t = 0; t < 4; t++) {
        int i = base + t;
        if (i < n) ex[i] = excl;
        excl += v[t];
    }
    if (tid == 255) bsum[blockIdx.x] = sh[255];
}

__global__ void k_scanB(const int* __restrict__ bsum, int* __restrict__ bexc, int nb) {
    __shared__ int sh[256];
    int tid = threadIdx.x;
    int s = (tid < nb) ? bsum[tid] : 0;
    sh[tid] = s;
    __syncthreads();
    for (int off = 1; off < 256; off <<= 1) {
        int t = (tid >= off) ? sh[tid - off] : 0;
        __syncthreads();
        sh[tid] += t;
        __syncthreads();
    }
    bexc[tid] = sh[tid] - s;
}

__global__ void k_scanC(int* __restrict__ starts, const int* __restrict__ bexc, int n) {
    int i = blockIdx.x * 256 + threadIdx.x;
    if (i < n) starts[i] += bexc[i >> 10];
}

// ---------------- CSR fill (by destination), packed (src,weight) ----------------
__global__ void k_fill(const int* __restrict__ ei, const float* __restrict__ dinv,
                       const int* __restrict__ starts, int* __restrict__ cursor,
                       uint2* __restrict__ edges, int e) {
    int i = blockIdx.x * 256 + threadIdx.x;
    if (i < e) {
        int r = ei[i];          // source
        int c = ei[e + i];      // destination (aggregation index)
        int p = atomicAdd(&cursor[c], 1);
        edges[starts[c] + p] = make_uint2((unsigned int)r,
                                          __float_as_uint(dinv[r] * dinv[c]));
    }
}

// ---------------- W -> bf16 B^T layout [JP][KP], zero-padded ----------------
__global__ void k_twb(const float* __restrict__ W, unsigned short* __restrict__ wbp) {
    int idx = blockIdx.x * 256 + threadIdx.x;
    if (idx < JP * KP) {
        int j = idx / KP, k = idx - j * KP;
        wbp[idx] = (j < D && k < D) ? f2bu(W[j * D + k]) : (unsigned short)0;
    }
}

// ---------------- x -> bf16, row stride XP, zero pad k=300..303 ----------------
// one us8 unit (8 bf16) per thread; 38 units per row.
__global__ void k_cvtx(const float* __restrict__ x, us8* __restrict__ xbp, int n) {
    int g = blockIdx.x * 256 + threadIdx.x;
    if (g >= n * 38) return;
    int row = g / 38, c = g - row * 38;
    int k = c * 8;
    const float* xr = x + (size_t)row * D + k;
    us8 u;
    if (k + 8 <= D) {
        float4 va = *(const float4*)xr;
        float4 vb = *(const float4*)(xr + 4);
        u[0] = f2bu(va.x); u[1] = f2bu(va.y); u[2] = f2bu(va.z); u[3] = f2bu(va.w);
        u[4] = f2bu(vb.x); u[5] = f2bu(vb.y); u[6] = f2bu(vb.z); u[7] = f2bu(vb.w);
    } else {                       // c == 37: k = 296..303, valid 296..299
        float4 va = *(const float4*)xr;
        u[0] = f2bu(va.x); u[1] = f2bu(va.y); u[2] = f2bu(va.z); u[3] = f2bu(va.w);
        u[4] = 0; u[5] = 0; u[6] = 0; u[7] = 0;
    }
    xbp[g] = u;
}

// ------ z = x @ W^T in bf16: MFMA, LDS-staged W (kg-major), 2 row-tiles/wave ------
// block = 4 waves = 128 rows; wave = 32 rows x 304 cols. A = bf16 xbp (stride XP).
__global__ __launch_bounds__(256)
void k_zmm(const unsigned short* __restrict__ xbp, const unsigned short* __restrict__ wbp,
           unsigned short* __restrict__ zb, int n) {
    __shared__ unsigned short Bsh[2][JP * 32];   // 2 x 19456 B
    int tid = threadIdx.x;
    int lane = tid & 63, wid = tid >> 6;
    int r0 = blockIdx.x * 128 + wid * 32;
    int lrow = lane & 15, kg = lane >> 4;

    int goff[5];
#pragma unroll
    for (int j = 0; j < 5; j++) {
        int i = wid + 4 * j;
        if (i < 19) {
            int u = i * 64 + lane;
            int kgs = u / 304;
            int rs  = u - kgs * 304;
            goff[j] = rs * (KP * 2) + kgs * 16;
        }
    }
    const char* wb = (const char*)wbp;

    int ar0 = r0 + lrow;      if (ar0 >= n) ar0 = n - 1;
    int ar1 = r0 + 16 + lrow; if (ar1 >= n) ar1 = n - 1;
    // A-unit index kk*4+kg may reach 39 (k up to 320): reads spill into the next
    // row (finite bf16) but multiply zero-padded W cols k>=300 -> contribute 0.
    const us8* ap0 = (const us8*)(xbp + (size_t)ar0 * XP);
    const us8* ap1 = (const us8*)(xbp + (size_t)ar1 * XP);

    f32x4 acc0[NT], acc1[NT];
#pragma unroll
    for (int t = 0; t < NT; t++) {
        acc0[t] = f32x4{0.f, 0.f, 0.f, 0.f};
        acc1[t] = f32x4{0.f, 0.f, 0.f, 0.f};
    }

    {
        char* lb = (char*)&Bsh[0][0];
#pragma unroll
        for (int j = 0; j < 5; j++) {
            int i = wid + 4 * j;
            if (i < 19) gload_lds16(wb + goff[j], lb + i * 1024);
        }
    }
    us8 a0 = ap0[kg], a1 = ap1[kg];
    __syncthreads();

    for (int kk = 0; kk < KP / 32; kk++) {
        if (kk < KP / 32 - 1) {
            char* lb = (char*)&Bsh[(kk + 1) & 1][0];
            int gofs = (kk + 1) * 64;
#pragma unroll
            for (int j = 0; j < 5; j++) {
                int i = wid + 4 * j;
                if (i < 19) gload_lds16(wb + goff[j] + gofs, lb + i * 1024);
            }
        }
        us8 a0n = a0, a1n = a1;
        if (kk < KP / 32 - 1) {
            a0n = ap0[(kk + 1) * 4 + kg];
            a1n = ap1[(kk + 1) * 4 + kg];
        }
        const unsigned short* bbase = &Bsh[kk & 1][0] + (kg * 304 + lrow) * 8;
        bf16x8 av0 = __builtin_bit_cast(bf16x8, a0);
        bf16x8 av1 = __builtin_bit_cast(bf16x8, a1);
#pragma unroll
        for (int t = 0; t < NT; t++) {
            bf16x8 bv = __builtin_bit_cast(bf16x8, *(const us8*)(bbase + t * 128));
            acc0[t] = __builtin_amdgcn_mfma_f32_16x16x32_bf16(av0, bv, acc0[t], 0, 0, 0);
            acc1[t] = __builtin_amdgcn_mfma_f32_16x16x32_bf16(av1, bv, acc1[t], 0, 0, 0);
        }
        a0 = a0n; a1 = a1n;
        __syncthreads();
    }

    // store z rows (bf16; cols 300..303 hold zeros from zero W cols)
#pragma unroll
    for (int r = 0; r < 4; r++) {
        int g0 = r0 + kg * 4 + r;          // C/D: row=(lane>>4)*4+reg
        int g1 = r0 + 16 + kg * 4 + r;
        unsigned short* zp0 = zb + (size_t)g0 * JP;
        unsigned short* zp1 = zb + (size_t)g1 * JP;
#pragma unroll
        for (int t = 0; t < NT; t++) {
            int j = t * 16 + lrow;
            if (g0 < n) zp0[j] = f2bu(acc0[t][r]);
            if (g1 < n) zp1[j] = f2bu(acc1[t][r]);
        }
    }
}

// ------ gather on z + fused epilogue: self-loop, bias, relu, L2-norm, fp32 out ------
// z row = 76 uint2 (304 bf16). lane covers uint2 slots {lane} + {64+lane if lane<12}.
__global__ void k_zgather(const uint2* __restrict__ zb2, const uint2* __restrict__ edges,
                          const int* __restrict__ starts, const int* __restrict__ deg,
                          const float* __restrict__ dinv, const float* __restrict__ bias,
                          float* __restrict__ out, int n) {
    int w = (blockIdx.x * blockDim.x + threadIdx.x) >> 6;
    if (w >= n) return;
    int lane = threadIdx.x & 63;
    int s = starts[w];
    int cnt = deg[w];             // in-degree (edges only)
    float dc = dinv[w];
    const bool p2 = lane < 12;    // slots 64..75
    float a0 = 0.f, a1 = 0.f, a2 = 0.f, a3 = 0.f;
    float a4 = 0.f, a5 = 0.f, a6 = 0.f, a7 = 0.f;
    const uint2 Z = make_uint2(0u, 0u);

#define GACC(ua, ub, wgt)                                                     \
    {                                                                         \
        a0 += (wgt) * bulo((ua).x); a1 += (wgt) * buhi((ua).x);               \
        a2 += (wgt) * bulo((ua).y); a3 += (wgt) * buhi((ua).y);               \
        a4 += (wgt) * bulo((ub).x); a5 += (wgt) * buhi((ub).x);               \
        a6 += (wgt) * bulo((ub).y); a7 += (wgt) * buhi((ub).y);               \
    }

    int t = 0;
    for (; t + 4 <= cnt; t += 4) {
        uint2 e0 = edges[s + t],     e1 = edges[s + t + 1];
        uint2 e2 = edges[s + t + 2], e3 = edges[s + t + 3];
        const uint2* q0 = zb2 + (size_t)e0.x * 76 + lane;
        const uint2* q1 = zb2 + (size_t)e1.x * 76 + lane;
        const uint2* q2 = zb2 + (size_t)e2.x * 76 + lane;
        const uint2* q3 = zb2 + (size_t)e3.x * 76 + lane;
        uint2 u0a = q0[0], u1a = q1[0], u2a = q2[0], u3a = q3[0];
        uint2 u0b = p2 ? q0[64] : Z;
        uint2 u1b = p2 ? q1[64] : Z;
        uint2 u2b = p2 ? q2[64] : Z;
        uint2 u3b = p2 ? q3[64] : Z;
        float w0 = __uint_as_float(e0.y), w1 = __uint_as_float(e1.y);
        float w2 = __uint_as_float(e2.y), w3 = __uint_as_float(e3.y);
        GACC(u0a, u0b, w0);
        GACC(u1a, u1b, w1);
        GACC(u2a, u2b, w2);
        GACC(u3a, u3b, w3);
    }
    for (; t < cnt; t++) {
        uint2 ed = edges[s + t];
        float wg = __uint_as_float(ed.y);
        const uint2* q = zb2 + (size_t)ed.x * 76 + lane;
        uint2 ua = q[0];
        uint2 ub = p2 ? q[64] : Z;
        GACC(ua, ub, wg);
    }
    {
        float sw = dc * dc;   // self loop
        const uint2* q = zb2 + (size_t)w * 76 + lane;
        uint2 ua = q[0];
        uint2 ub = p2 ? q[64] : Z;
        GACC(ua, ub, sw);
    }
#undef GACC

    // bias + relu
    float4 b0 = *(const float4*)(bias + 4 * lane);        // dims 4l..4l+3 (<256)
    float4 b1 = {0.f, 0.f, 0.f, 0.f};
    const bool wr2 = lane < 11;                           // dims 256..299
    if (wr2) b1 = *(const float4*)(bias + 256 + 4 * lane);
    float v0 = fmaxf(a0 + b0.x, 0.f), v1 = fmaxf(a1 + b0.y, 0.f);
    float v2 = fmaxf(a2 + b0.z, 0.f), v3 = fmaxf(a3 + b0.w, 0.f);
    float v4 = fmaxf(a4 + b1.x, 0.f), v5 = fmaxf(a5 + b1.y, 0.f);
    float v6 = fmaxf(a6 + b1.z, 0.f), v7 = fmaxf(a7 + b1.w, 0.f);
    float sq = v0 * v0 + v1 * v1 + v2 * v2 + v3 * v3
             + v4 * v4 + v5 * v5 + v6 * v6 + v7 * v7;
    sq += __shfl_xor(sq, 1);
    sq += __shfl_xor(sq, 2);
    sq += __shfl_xor(sq, 4);
    sq += __shfl_xor(sq, 8);
    sq += __shfl_xor(sq, 16);
    sq += __shfl_xor(sq, 32);
    float sc = rsqrtf(fmaxf(sq, 1e-24f));   // == 1/max(sqrt(sq),1e-12)

    float* op = out + (size_t)w * D;
    *(float4*)(op + 4 * lane) = make_float4(v0 * sc, v1 * sc, v2 * sc, v3 * sc);
    if (wr2)
        *(float4*)(op + 256 + 4 * lane) = make_float4(v4 * sc, v5 * sc, v6 * sc, v7 * sc);
}

// ---------------- host launch ----------------
extern "C" void kernel_launch(void* const* d_in, const int* in_sizes, int n_in,
                              void* d_out, int out_size, void* d_ws, size_t ws_size,
                              hipStream_t stream) {
    const float* x  = (const float*)d_in[0];
    const int*   ei = (const int*)d_in[1];
    const float* W  = (const float*)d_in[2];
    const float* b  = (const float*)d_in[3];
    float* out = (float*)d_out;
    int n = in_sizes[0] / D;
    int e = in_sizes[1] / 2;

    char* p = (char*)d_ws;
    unsigned short* zb = (unsigned short*)p; p += (size_t)n * JP * 2;
    int* deg = (int*)p;         p += (size_t)n * 4;
    int* cursor = (int*)p;      p += (size_t)n * 4;   // adjacent to deg for one memset
    float* dinv = (float*)p;    p += (size_t)n * 4;
    int* starts = (int*)p;      p += (size_t)n * 4;
    p = (char*)(((uintptr_t)p + 15) & ~(uintptr_t)15);
    uint2* edges = (uint2*)p;   p += (size_t)e * 8;
    int* bsum = (int*)p;        p += 256 * 4;
    int* bexc = (int*)p;        p += 256 * 4;
    p = (char*)(((uintptr_t)p + 15) & ~(uintptr_t)15);
    unsigned short* wbp = (unsigned short*)p; p += (size_t)JP * KP * 2;
    p = (char*)(((uintptr_t)p + 15) & ~(uintptr_t)15);
    unsigned short* xbp = (unsigned short*)p; p += (size_t)n * XP * 2;

    int nb = (n + 1023) / 1024;

    hipMemsetAsync(deg, 0, (size_t)n * 8, stream);   // deg + cursor
    k_count<<<(e + 255) / 256, 256, 0, stream>>>(ei + e, deg, e);
    k_scanA<<<nb, 256, 0, stream>>>(deg, starts, dinv, bsum, n);
    k_scanB<<<1, 256, 0, stream>>>(bsum, bexc, nb);
    k_scanC<<<(n + 255) / 256, 256, 0, stream>>>(starts, bexc, n);
    k_fill <<<(e + 255) / 256, 256, 0, stream>>>(ei, dinv, starts, cursor, edges, e);
    k_twb  <<<(JP * KP + 255) / 256, 256, 0, stream>>>(W, wbp);
    k_cvtx <<<(n * 38 + 255) / 256, 256, 0, stream>>>(x, (us8*)xbp, n);
    k_zmm  <<<(n + 127) / 128, 256, 0, stream>>>(xbp, wbp, zb, n);
    k_zgather<<<(n + 3) / 4, 256, 0, stream>>>((const uint2*)zb, edges, starts, deg,
                                               dinv, b, out, n);
}

// Round 8
// 291.863 us; speedup vs baseline: 1.0139x; 1.0139x over previous
//
#include <hip/hip_runtime.h>
#include <hip/hip_bf16.h>
#include <stdint.h>

#define D 300
#define KP 320   // K padded to 10*32 (MFMA k-loop extent)
#define JP 304   // out-col padded to 19*16; also zb row stride
#define NT 19    // col tiles (16 wide) per wave

typedef __hip_bfloat16 bf16;
typedef __bf16 bf16x8 __attribute__((ext_vector_type(8)));
typedef unsigned short us8 __attribute__((ext_vector_type(8)));
typedef float f32x4 __attribute__((ext_vector_type(4)));

static __device__ __forceinline__ unsigned short f2bu(float f) {
    bf16 h = __float2bfloat16(f);
    return *reinterpret_cast<unsigned short*>(&h);
}
static __device__ __forceinline__ float bulo(unsigned int u) {
    return __uint_as_float(u << 16);
}
static __device__ __forceinline__ float buhi(unsigned int u) {
    return __uint_as_float(u & 0xffff0000u);
}
static __device__ __forceinline__ unsigned int packbf(float lo, float hi) {
    return (unsigned int)f2bu(lo) | ((unsigned int)f2bu(hi) << 16);
}
static __device__ __forceinline__ void gload_lds16(const void* g, void* l) {
    __builtin_amdgcn_global_load_lds(
        (const __attribute__((address_space(1))) unsigned int*)g,
        (__attribute__((address_space(3))) unsigned int*)l, 16, 0, 0);
}

// ---------------- count in-degree (deg pre-zeroed by memset) ----------------
__global__ void k_count(const int* __restrict__ col, int* __restrict__ deg, int e) {
    int i = blockIdx.x * 256 + threadIdx.x;
    if (i < e) atomicAdd(&deg[col[i]], 1);
}

// ------- exclusive scan of deg (=in-degree) + fused dinv = rsqrt(deg+1) -------
__global__ void k_scanA(const int* __restrict__ deg, int* __restrict__ ex,
                        float* __restrict__ dinv, int* __restrict__ bsum, int n) {
    __shared__ int sh[256];
    int tid = threadIdx.x;
    int base = blockIdx.x * 1024 + tid * 4;
    int v[4]; int s = 0;
#pragma unroll
    for (int t = 0; t < 4; t++) {
        int i = base + t;
        v[t] = (i < n) ? deg[i] : 0;
        if (i < n) dinv[i] = rsqrtf((float)(v[t] + 1));   // +1 = self loop
        s += v[t];
    }
    sh[tid] = s;
    __syncthreads();
    for (int off = 1; off < 256; off <<= 1) {
        int t = (tid >= off) ? sh[tid - off] : 0;
        __syncthreads();
        sh[tid] += t;
        __syncthreads();
    }
    int excl = sh[tid] - s;
#pragma unroll
    for (int t = 0; t < 4; t++) {
        int i = base + t;
        if (i < n) ex[i] = excl;
        excl += v[t];
    }
    if (tid == 255) bsum[blockIdx.x] = sh[255];
}

__global__ void k_scanB(const int* __restrict__ bsum, int* __restrict__ bexc, int nb) {
    __shared__ int sh[256];
    int tid = threadIdx.x;
    int s = (tid < nb) ? bsum[tid] : 0;
    sh[tid] = s;
    __syncthreads();
    for (int off = 1; off < 256; off <<= 1) {
        int t = (tid >= off) ? sh[tid - off] : 0;
        __syncthreads();
        sh[tid] += t;
        __syncthreads();
    }
    bexc[tid] = sh[tid] - s;
}

__global__ void k_scanC(int* __restrict__ starts, const int* __restrict__ bexc, int n) {
    int i = blockIdx.x * 256 + threadIdx.x;
    if (i < n) starts[i] += bexc[i >> 10];
}

// ---------------- CSR fill (by destination), packed (src,weight) ----------------
__global__ void k_fill(const int* __restrict__ ei, const float* __restrict__ dinv,
                       const int* __restrict__ starts, int* __restrict__ cursor,
                       uint2* __restrict__ edges, int e) {
    int i = blockIdx.x * 256 + threadIdx.x;
    if (i < e) {
        int r = ei[i];          // source
        int c = ei[e + i];      // destination (aggregation index)
        int p = atomicAdd(&cursor[c], 1);
        edges[starts[c] + p] = make_uint2((unsigned int)r,
                                          __float_as_uint(dinv[r] * dinv[c]));
    }
}

// ---------------- W -> bf16 B^T layout [JP][KP], zero-padded ----------------
__global__ void k_twb(const float* __restrict__ W, unsigned short* __restrict__ wbp) {
    int idx = blockIdx.x * 256 + threadIdx.x;
    if (idx < JP * KP) {
        int j = idx / KP, k = idx - j * KP;
        wbp[idx] = (j < D && k < D) ? f2bu(W[j * D + k]) : (unsigned short)0;
    }
}

// ------ z = x @ W^T: MFMA; W LDS-staged (gload_lds, kg-major, dbuf);
//        A staged fp32->reg->bf16->LDS (T14 split, kg-major, dbuf). ------
// block = 4 waves = 128 rows; wave = 32 rows x 304 cols. Reads fp32 x directly.
__global__ __launch_bounds__(256)
void k_zmm(const float* __restrict__ x, const unsigned short* __restrict__ wbp,
           unsigned short* __restrict__ zb, int n) {
    __shared__ unsigned short Wsh[2][JP * 32];   // 2 x 19456 B, unit = kg*304 + row
    __shared__ unsigned short Ash[2][4096];      // 2 x 8192 B,  [kg][128 rows][8 bf16]
    int tid = threadIdx.x;
    int lane = tid & 63, wid = tid >> 6;
    int r0 = blockIdx.x * 128 + wid * 32;
    int lrow = lane & 15, kg = lane >> 4;

    // ---- W staging offsets: slots i = wid + 4j (i < 19), 1024 B each ----
    int goff[5];
#pragma unroll
    for (int j = 0; j < 5; j++) {
        int i = wid + 4 * j;
        if (i < 19) {
            int u = i * 64 + lane;
            int kgs = u / 304;
            int rs  = u - kgs * 304;
            goff[j] = rs * (KP * 2) + kgs * 16;
        }
    }
    const char* wb = (const char*)wbp;

    // ---- A staging assignment: 4 units (16B fp32 -> 8B bf16) per thread ----
    // unit i = tid + 256*j : row = i>>3, u16 = i&7 (k = u16*4 within 32-k chunk)
    const float* asrc[4];   // row base (clamped)
    int akof[4];            // k offset within chunk (0,4,..28)
    int aldo[4];            // LDS byte offset (kg-major)
#pragma unroll
    for (int j = 0; j < 4; j++) {
        int i = tid + 256 * j;
        int r = i >> 3, u16 = i & 7;
        int rg = blockIdx.x * 128 + r; if (rg >= n) rg = n - 1;
        asrc[j] = x + (size_t)rg * D;
        akof[j] = u16 * 4;
        aldo[j] = (u16 >> 1) * 2048 + r * 16 + (u16 & 1) * 8;
    }

    f32x4 acc0[NT], acc1[NT];
#pragma unroll
    for (int t = 0; t < NT; t++) {
        acc0[t] = f32x4{0.f, 0.f, 0.f, 0.f};
        acc1[t] = f32x4{0.f, 0.f, 0.f, 0.f};
    }

    // ---- prologue: stage W0 + A0 ----
    {
        char* lb = (char*)&Wsh[0][0];
#pragma unroll
        for (int j = 0; j < 5; j++) {
            int i = wid + 4 * j;
            if (i < 19) gload_lds16(wb + goff[j], lb + i * 1024);
        }
        float4 lv[4];
#pragma unroll
        for (int j = 0; j < 4; j++) {
            int k = akof[j];                       // kk=0: k <= 28, no clamp needed
            lv[j] = *(const float4*)(asrc[j] + k);
        }
#pragma unroll
        for (int j = 0; j < 4; j++) {
            uint2 w2 = make_uint2(packbf(lv[j].x, lv[j].y), packbf(lv[j].z, lv[j].w));
            *(uint2*)((char*)&Ash[0][0] + aldo[j]) = w2;
        }
    }
    __syncthreads();

    const int arb0 = (wid * 32 + lrow) * 16;        // A frag byte offsets (row-major part)
    const int arb1 = (wid * 32 + 16 + lrow) * 16;

    for (int kk = 0; kk < KP / 32; kk++) {
        int cur = kk & 1, nxt = cur ^ 1;
        float4 lv[4];
        if (kk < KP / 32 - 1) {
            // stage next W chunk (async to LDS)
            char* lb = (char*)&Wsh[nxt][0];
            int gofs = (kk + 1) * 64;
#pragma unroll
            for (int j = 0; j < 5; j++) {
                int i = wid + 4 * j;
                if (i < 19) gload_lds16(wb + goff[j] + gofs, lb + i * 1024);
            }
            // issue next A loads (fp32) early
#pragma unroll
            for (int j = 0; j < 4; j++) {
                int k = (kk + 1) * 32 + akof[j];
                if (k > D - 4) k = D - 4;           // clamped dup; W cols >=300 are 0
                lv[j] = *(const float4*)(asrc[j] + k);
            }
        }
        // compute on current buffers
        us8 a0 = *(const us8*)((const char*)&Ash[cur][0] + kg * 2048 + arb0);
        us8 a1 = *(const us8*)((const char*)&Ash[cur][0] + kg * 2048 + arb1);
        const unsigned short* bbase = &Wsh[cur][0] + (kg * 304 + lrow) * 8;
        bf16x8 av0 = __builtin_bit_cast(bf16x8, a0);
        bf16x8 av1 = __builtin_bit_cast(bf16x8, a1);
#pragma unroll
        for (int t = 0; t < NT; t++) {
            bf16x8 bv = __builtin_bit_cast(bf16x8, *(const us8*)(bbase + t * 128));
            acc0[t] = __builtin_amdgcn_mfma_f32_16x16x32_bf16(av0, bv, acc0[t], 0, 0, 0);
            acc1[t] = __builtin_amdgcn_mfma_f32_16x16x32_bf16(av1, bv, acc1[t], 0, 0, 0);
        }
        if (kk < KP / 32 - 1) {
            // convert + write next A chunk (loads have landed by now)
#pragma unroll
            for (int j = 0; j < 4; j++) {
                uint2 w2 = make_uint2(packbf(lv[j].x, lv[j].y), packbf(lv[j].z, lv[j].w));
                *(uint2*)((char*)&Ash[nxt][0] + aldo[j]) = w2;
            }
        }
        __syncthreads();
    }

    // ---- store z rows (bf16; cols 300..303 are zeros via zero W cols) ----
#pragma unroll
    for (int r = 0; r < 4; r++) {
        int g0 = r0 + kg * 4 + r;          // C/D: row=(lane>>4)*4+reg
        int g1 = r0 + 16 + kg * 4 + r;
        unsigned short* zp0 = zb + (size_t)g0 * JP;
        unsigned short* zp1 = zb + (size_t)g1 * JP;
#pragma unroll
        for (int t = 0; t < NT; t++) {
            int j = t * 16 + lrow;
            if (g0 < n) zp0[j] = f2bu(acc0[t][r]);
            if (g1 < n) zp1[j] = f2bu(acc1[t][r]);
        }
    }
}

// ------ gather on z + fused epilogue: self-loop, bias, relu, L2-norm, fp32 out ------
// z row = 76 uint2 (304 bf16). lane covers uint2 slots {lane} + {64+lane if lane<12}.
__global__ void k_zgather(const uint2* __restrict__ zb2, const uint2* __restrict__ edges,
                          const int* __restrict__ starts, const int* __restrict__ deg,
                          const float* __restrict__ dinv, const float* __restrict__ bias,
                          float* __restrict__ out, int n) {
    int w = (blockIdx.x * blockDim.x + threadIdx.x) >> 6;
    if (w >= n) return;
    int lane = threadIdx.x & 63;
    int s = starts[w];
    int cnt = deg[w];             // in-degree (edges only)
    float dc = dinv[w];
    const bool p2 = lane < 12;    // slots 64..75
    float a0 = 0.f, a1 = 0.f, a2 = 0.f, a3 = 0.f;
    float a4 = 0.f, a5 = 0.f, a6 = 0.f, a7 = 0.f;
    const uint2 Z = make_uint2(0u, 0u);

#define GACC(ua, ub, wgt)                                                     \
    {                                                                         \
        a0 += (wgt) * bulo((ua).x); a1 += (wgt) * buhi((ua).x);               \
        a2 += (wgt) * bulo((ua).y); a3 += (wgt) * buhi((ua).y);               \
        a4 += (wgt) * bulo((ub).x); a5 += (wgt) * buhi((ub).x);               \
        a6 += (wgt) * bulo((ub).y); a7 += (wgt) * buhi((ub).y);               \
    }

    int t = 0;
    for (; t + 4 <= cnt; t += 4) {
        uint2 e0 = edges[s + t],     e1 = edges[s + t + 1];
        uint2 e2 = edges[s + t + 2], e3 = edges[s + t + 3];
        const uint2* q0 = zb2 + (size_t)e0.x * 76 + lane;
        const uint2* q1 = zb2 + (size_t)e1.x * 76 + lane;
        const uint2* q2 = zb2 + (size_t)e2.x * 76 + lane;
        const uint2* q3 = zb2 + (size_t)e3.x * 76 + lane;
        uint2 u0a = q0[0], u1a = q1[0], u2a = q2[0], u3a = q3[0];
        uint2 u0b = p2 ? q0[64] : Z;
        uint2 u1b = p2 ? q1[64] : Z;
        uint2 u2b = p2 ? q2[64] : Z;
        uint2 u3b = p2 ? q3[64] : Z;
        float w0 = __uint_as_float(e0.y), w1 = __uint_as_float(e1.y);
        float w2 = __uint_as_float(e2.y), w3 = __uint_as_float(e3.y);
        GACC(u0a, u0b, w0);
        GACC(u1a, u1b, w1);
        GACC(u2a, u2b, w2);
        GACC(u3a, u3b, w3);
    }
    for (; t < cnt; t++) {
        uint2 ed = edges[s + t];
        float wg = __uint_as_float(ed.y);
        const uint2* q = zb2 + (size_t)ed.x * 76 + lane;
        uint2 ua = q[0];
        uint2 ub = p2 ? q[64] : Z;
        GACC(ua, ub, wg);
    }
    {
        float sw = dc * dc;   // self loop
        const uint2* q = zb2 + (size_t)w * 76 + lane;
        uint2 ua = q[0];
        uint2 ub = p2 ? q[64] : Z;
        GACC(ua, ub, sw);
    }
#undef GACC

    // bias + relu
    float4 b0 = *(const float4*)(bias + 4 * lane);        // dims 4l..4l+3 (<256)
    float4 b1 = {0.f, 0.f, 0.f, 0.f};
    const bool wr2 = lane < 11;                           // dims 256..299
    if (wr2) b1 = *(const float4*)(bias + 256 + 4 * lane);
    float v0 = fmaxf(a0 + b0.x, 0.f), v1 = fmaxf(a1 + b0.y, 0.f);
    float v2 = fmaxf(a2 + b0.z, 0.f), v3 = fmaxf(a3 + b0.w, 0.f);
    float v4 = fmaxf(a4 + b1.x, 0.f), v5 = fmaxf(a5 + b1.y, 0.f);
    float v6 = fmaxf(a6 + b1.z, 0.f), v7 = fmaxf(a7 + b1.w, 0.f);
    float sq = v0 * v0 + v1 * v1 + v2 * v2 + v3 * v3
             + v4 * v4 + v5 * v5 + v6 * v6 + v7 * v7;
    sq += __shfl_xor(sq, 1);
    sq += __shfl_xor(sq, 2);
    sq += __shfl_xor(sq, 4);
    sq += __shfl_xor(sq, 8);
    sq += __shfl_xor(sq, 16);
    sq += __shfl_xor(sq, 32);
    float sc = rsqrtf(fmaxf(sq, 1e-24f));   // == 1/max(sqrt(sq),1e-12)

    float* op = out + (size_t)w * D;
    *(float4*)(op + 4 * lane) = make_float4(v0 * sc, v1 * sc, v2 * sc, v3 * sc);
    if (wr2)
        *(float4*)(op + 256 + 4 * lane) = make_float4(v4 * sc, v5 * sc, v6 * sc, v7 * sc);
}

// ---------------- host launch ----------------
extern "C" void kernel_launch(void* const* d_in, const int* in_sizes, int n_in,
                              void* d_out, int out_size, void* d_ws, size_t ws_size,
                              hipStream_t stream) {
    const float* x  = (const float*)d_in[0];
    const int*   ei = (const int*)d_in[1];
    const float* W  = (const float*)d_in[2];
    const float* b  = (const float*)d_in[3];
    float* out = (float*)d_out;
    int n = in_sizes[0] / D;
    int e = in_sizes[1] / 2;

    char* p = (char*)d_ws;
    unsigned short* zb = (unsigned short*)p; p += (size_t)n * JP * 2;
    int* deg = (int*)p;         p += (size_t)n * 4;
    int* cursor = (int*)p;      p += (size_t)n * 4;   // adjacent to deg for one memset
    float* dinv = (float*)p;    p += (size_t)n * 4;
    int* starts = (int*)p;      p += (size_t)n * 4;
    p = (char*)(((uintptr_t)p + 15) & ~(uintptr_t)15);
    uint2* edges = (uint2*)p;   p += (size_t)e * 8;
    int* bsum = (int*)p;        p += 256 * 4;
    int* bexc = (int*)p;        p += 256 * 4;
    p = (char*)(((uintptr_t)p + 15) & ~(uintptr_t)15);
    unsigned short* wbp = (unsigned short*)p; p += (size_t)JP * KP * 2;

    int nb = (n + 1023) / 1024;

    hipMemsetAsync(deg, 0, (size_t)n * 8, stream);   // deg + cursor
    k_count<<<(e + 255) / 256, 256, 0, stream>>>(ei + e, deg, e);
    k_scanA<<<nb, 256, 0, stream>>>(deg, starts, dinv, bsum, n);
    k_scanB<<<1, 256, 0, stream>>>(bsum, bexc, nb);
    k_scanC<<<(n + 255) / 256, 256, 0, stream>>>(starts, bexc, n);
    k_fill <<<(e + 255) / 256, 256, 0, stream>>>(ei, dinv, starts, cursor, edges, e);
    k_twb  <<<(JP * KP + 255) / 256, 256, 0, stream>>>(W, wbp);
    k_zmm  <<<(n + 127) / 128, 256, 0, stream>>>(x, wbp, zb, n);
    k_zgather<<<(n + 3) / 4, 256, 0, stream>>>((const uint2*)zb, edges, starts, deg,
                                               dinv, b, out, n);
}

// Round 10
// 276.976 us; speedup vs baseline: 1.0684x; 1.0537x over previous
//
#include <hip/hip_runtime.h>
#include <hip/hip_bf16.h>
#include <stdint.h>

#define D 300
#define KP 320   // K padded to 10*32 (MFMA k-loop extent)
#define JP 304   // out-col padded to 19*16; also zb row stride
#define NT 19    // col tiles (16 wide) per wave

typedef __hip_bfloat16 bf16;
typedef __bf16 bf16x8 __attribute__((ext_vector_type(8)));
typedef unsigned short us8 __attribute__((ext_vector_type(8)));
typedef float f32x4 __attribute__((ext_vector_type(4)));

static __device__ __forceinline__ unsigned short f2bu(float f) {
    bf16 h = __float2bfloat16(f);
    return *reinterpret_cast<unsigned short*>(&h);
}
static __device__ __forceinline__ float bulo(unsigned int u) {
    return __uint_as_float(u << 16);
}
static __device__ __forceinline__ float buhi(unsigned int u) {
    return __uint_as_float(u & 0xffff0000u);
}
static __device__ __forceinline__ void gload_lds16(const void* g, void* l) {
    __builtin_amdgcn_global_load_lds(
        (const __attribute__((address_space(1))) unsigned int*)g,
        (__attribute__((address_space(3))) unsigned int*)l, 16, 0, 0);
}

// ---------------- count in-degree (deg pre-zeroed by memset) ----------------
__global__ void k_count(const int* __restrict__ col, int* __restrict__ deg, int e) {
    int i = blockIdx.x * 256 + threadIdx.x;
    if (i < e) atomicAdd(&deg[col[i]], 1);
}

// ------- exclusive scan of deg (=in-degree) + fused dinv = rsqrt(deg+1) -------
__global__ void k_scanA(const int* __restrict__ deg, int* __restrict__ ex,
                        float* __restrict__ dinv, int* __restrict__ bsum, int n) {
    __shared__ int sh[256];
    int tid = threadIdx.x;
    int base = blockIdx.x * 1024 + tid * 4;
    int v[4]; int s = 0;
#pragma unroll
    for (int t = 0; t < 4; t++) {
        int i = base + t;
        v[t] = (i < n) ? deg[i] : 0;
        if (i < n) dinv[i] = rsqrtf((float)(v[t] + 1));   // +1 = self loop
        s += v[t];
    }
    sh[tid] = s;
    __syncthreads();
    for (int off = 1; off < 256; off <<= 1) {
        int t = (tid >= off) ? sh[tid - off] : 0;
        __syncthreads();
        sh[tid] += t;
        __syncthreads();
    }
    int excl = sh[tid] - s;
#pragma unroll
    for (int t = 0; t < 4; t++) {
        int i = base + t;
        if (i < n) ex[i] = excl;
        excl += v[t];
    }
    if (tid == 255) bsum[blockIdx.x] = sh[255];
}

__global__ void k_scanB(const int* __restrict__ bsum, int* __restrict__ bexc, int nb) {
    __shared__ int sh[256];
    int tid = threadIdx.x;
    int s = (tid < nb) ? bsum[tid] : 0;
    sh[tid] = s;
    __syncthreads();
    for (int off = 1; off < 256; off <<= 1) {
        int t = (tid >= off) ? sh[tid - off] : 0;
        __syncthreads();
        sh[tid] += t;
        __syncthreads();
    }
    bexc[tid] = sh[tid] - s;
}

__global__ void k_scanC(int* __restrict__ starts, const int* __restrict__ bexc, int n) {
    int i = blockIdx.x * 256 + threadIdx.x;
    if (i < n) starts[i] += bexc[i >> 10];
}

// ---------------- CSR fill (by destination), packed (src,weight) ----------------
__global__ void k_fill(const int* __restrict__ ei, const float* __restrict__ dinv,
                       const int* __restrict__ starts, int* __restrict__ cursor,
                       uint2* __restrict__ edges, int e) {
    int i = blockIdx.x * 256 + threadIdx.x;
    if (i < e) {
        int r = ei[i];          // source
        int c = ei[e + i];      // destination (aggregation index)
        int p = atomicAdd(&cursor[c], 1);
        edges[starts[c] + p] = make_uint2((unsigned int)r,
                                          __float_as_uint(dinv[r] * dinv[c]));
    }
}

// ---------------- W -> bf16 B^T layout [JP][KP], zero-padded ----------------
__global__ void k_twb(const float* __restrict__ W, unsigned short* __restrict__ wbp) {
    int idx = blockIdx.x * 256 + threadIdx.x;
    if (idx < JP * KP) {
        int j = idx / KP, k = idx - j * KP;
        wbp[idx] = (j < D && k < D) ? f2bu(W[j * D + k]) : (unsigned short)0;
    }
}

// ------ z = x @ W^T: MFMA. Single-buffered LDS (2-barrier k-step, occupancy-first).
//        W: gload_lds kg-major (19 KB). A: raw fp32 via gload_lds (8 KB),
//        fp32->bf16 at fragment-read time. block = 4 waves x 16 rows = 64 rows.
__global__ __launch_bounds__(256)
void k_zmm(const float* __restrict__ x, const unsigned short* __restrict__ wbp,
           unsigned short* __restrict__ zb, int n) {
    __shared__ unsigned short Wsh[JP * 32];   // 19456 B; unit u16B = kg*304 + row
    __shared__ float Ash[2048];               // 8192 B; [kg:4][row:64][8 floats]
    int tid = threadIdx.x;
    int lane = tid & 63, wid = tid >> 6;
    int r0 = blockIdx.x * 64 + wid * 16;
    int lrow = lane & 15, kg = lane >> 4;

    // ---- W staging offsets: slots i = wid + 4j (i < 19), 1024 B each ----
    int goff[5];
#pragma unroll
    for (int j = 0; j < 5; j++) {
        int i = wid + 4 * j;
        if (i < 19) {
            int u = i * 64 + lane;
            int kgs = u / 304;
            int rs  = u - kgs * 304;
            goff[j] = rs * (KP * 2) + kgs * 16;   // + kk*64 per k-step
        }
    }
    const char* wb = (const char*)wbp;

    // ---- A staging: 2 units (16 B fp32) per thread; LDS linear = kg-major ----
    // unit u: kg = u>>7, row = (u&127)>>1, half = u&1
    const float* ab[2];
    int thr[2];
#pragma unroll
    for (int j = 0; j < 2; j++) {
        int u = tid + 256 * j;
        int kgs = u >> 7, rem = u & 127, row = rem >> 1, half = rem & 1;
        int rg = blockIdx.x * 64 + row; if (rg >= n) rg = n - 1;
        int off = kgs * 8 + half * 4;             // float offset within k-chunk
        ab[j] = x + (size_t)rg * D + off;
        thr[j] = 296 - off;                       // max kk*32 with full in-row float4
    }

    f32x4 acc[NT];
#pragma unroll
    for (int t = 0; t < NT; t++) acc[t] = f32x4{0.f, 0.f, 0.f, 0.f};

    const float* afp = &Ash[kg * 512 + (wid * 16 + lrow) * 8];
    const unsigned short* bbase = &Wsh[0] + (kg * 304 + lrow) * 8;

    for (int kk = 0; kk < KP / 32; kk++) {
        // stage W chunk kk (async, L2-hot)
#pragma unroll
        for (int j = 0; j < 5; j++) {
            int i = wid + 4 * j;
            if (i < 19) gload_lds16(wb + goff[j] + kk * 64, (char*)&Wsh[0] + i * 1024);
        }
        // stage A chunk kk (async, raw fp32; clamp OOB-k units to x[0..3] -- they
        // multiply zero-padded W cols k>=300, contributing 0)
        {
            const float* s0 = (kk * 32 <= thr[0]) ? ab[0] + kk * 32 : x;
            const float* s1 = (kk * 32 <= thr[1]) ? ab[1] + kk * 32 : x;
            gload_lds16(s0, (char*)&Ash[0] + wid * 1024);
            gload_lds16(s1, (char*)&Ash[0] + 4096 + wid * 1024);
        }
        __syncthreads();   // drains vmcnt: staging complete

        // A fragment: 8 fp32 -> bf16x8
        float4 pa = *(const float4*)afp;
        float4 pb = *(const float4*)(afp + 4);
        us8 au;
        au[0] = f2bu(pa.x); au[1] = f2bu(pa.y); au[2] = f2bu(pa.z); au[3] = f2bu(pa.w);
        au[4] = f2bu(pb.x); au[5] = f2bu(pb.y); au[6] = f2bu(pb.z); au[7] = f2bu(pb.w);
        bf16x8 av = __builtin_bit_cast(bf16x8, au);
#pragma unroll
        for (int t = 0; t < NT; t++) {
            bf16x8 bv = __builtin_bit_cast(bf16x8, *(const us8*)(bbase + t * 128));
            acc[t] = __builtin_amdgcn_mfma_f32_16x16x32_bf16(av, bv, acc[t], 0, 0, 0);
        }
        __syncthreads();   // all reads done before next k-step overwrites buffers
    }

    // ---- store z rows (bf16; cols 300..303 are zeros via zero W cols) ----
#pragma unroll
    for (int r = 0; r < 4; r++) {
        int g0 = r0 + kg * 4 + r;          // C/D: row=(lane>>4)*4+reg
        if (g0 < n) {
            unsigned short* zp0 = zb + (size_t)g0 * JP;
#pragma unroll
            for (int t = 0; t < NT; t++) {
                int j = t * 16 + lrow;
                zp0[j] = f2bu(acc[t][r]);
            }
        }
    }
}

// ------ gather on z + fused epilogue: self-loop, bias, relu, L2-norm, fp32 out ------
// z row = 76 uint2 (304 bf16). lane covers uint2 slots {lane} + {64+lane if lane<12}.
__global__ void k_zgather(const uint2* __restrict__ zb2, const uint2* __restrict__ edges,
                          const int* __restrict__ starts, const int* __restrict__ deg,
                          const float* __restrict__ dinv, const float* __restrict__ bias,
                          float* __restrict__ out, int n) {
    int w = (blockIdx.x * blockDim.x + threadIdx.x) >> 6;
    if (w >= n) return;
    int lane = threadIdx.x & 63;
    int s = starts[w];
    int cnt = deg[w];             // in-degree (edges only)
    float dc = dinv[w];
    const bool p2 = lane < 12;    // slots 64..75
    float a0 = 0.f, a1 = 0.f, a2 = 0.f, a3 = 0.f;
    float a4 = 0.f, a5 = 0.f, a6 = 0.f, a7 = 0.f;
    const uint2 Z = make_uint2(0u, 0u);

#define GACC(ua, ub, wgt)                                                     \
    {                                                                         \
        a0 += (wgt) * bulo((ua).x); a1 += (wgt) * buhi((ua).x);               \
        a2 += (wgt) * bulo((ua).y); a3 += (wgt) * buhi((ua).y);               \
        a4 += (wgt) * bulo((ub).x); a5 += (wgt) * buhi((ub).x);               \
        a6 += (wgt) * bulo((ub).y); a7 += (wgt) * buhi((ub).y);               \
    }

    int t = 0;
    for (; t + 4 <= cnt; t += 4) {
        uint2 e0 = edges[s + t],     e1 = edges[s + t + 1];
        uint2 e2 = edges[s + t + 2], e3 = edges[s + t + 3];
        const uint2* q0 = zb2 + (size_t)e0.x * 76 + lane;
        const uint2* q1 = zb2 + (size_t)e1.x * 76 + lane;
        const uint2* q2 = zb2 + (size_t)e2.x * 76 + lane;
        const uint2* q3 = zb2 + (size_t)e3.x * 76 + lane;
        uint2 u0a = q0[0], u1a = q1[0], u2a = q2[0], u3a = q3[0];
        uint2 u0b = p2 ? q0[64] : Z;
        uint2 u1b = p2 ? q1[64] : Z;
        uint2 u2b = p2 ? q2[64] : Z;
        uint2 u3b = p2 ? q3[64] : Z;
        float w0 = __uint_as_float(e0.y), w1 = __uint_as_float(e1.y);
        float w2 = __uint_as_float(e2.y), w3 = __uint_as_float(e3.y);
        GACC(u0a, u0b, w0);
        GACC(u1a, u1b, w1);
        GACC(u2a, u2b, w2);
        GACC(u3a, u3b, w3);
    }
    for (; t < cnt; t++) {
        uint2 ed = edges[s + t];
        float wg = __uint_as_float(ed.y);
        const uint2* q = zb2 + (size_t)ed.x * 76 + lane;
        uint2 ua = q[0];
        uint2 ub = p2 ? q[64] : Z;
        GACC(ua, ub, wg);
    }
    {
        float sw = dc * dc;   // self loop
        const uint2* q = zb2 + (size_t)w * 76 + lane;
        uint2 ua = q[0];
        uint2 ub = p2 ? q[64] : Z;
        GACC(ua, ub, sw);
    }
#undef GACC

    // bias + relu
    float4 b0 = *(const float4*)(bias + 4 * lane);        // dims 4l..4l+3 (<256)
    float4 b1 = {0.f, 0.f, 0.f, 0.f};
    const bool wr2 = lane < 11;                           // dims 256..299
    if (wr2) b1 = *(const float4*)(bias + 256 + 4 * lane);
    float v0 = fmaxf(a0 + b0.x, 0.f), v1 = fmaxf(a1 + b0.y, 0.f);
    float v2 = fmaxf(a2 + b0.z, 0.f), v3 = fmaxf(a3 + b0.w, 0.f);
    float v4 = fmaxf(a4 + b1.x, 0.f), v5 = fmaxf(a5 + b1.y, 0.f);
    float v6 = fmaxf(a6 + b1.z, 0.f), v7 = fmaxf(a7 + b1.w, 0.f);
    float sq = v0 * v0 + v1 * v1 + v2 * v2 + v3 * v3
             + v4 * v4 + v5 * v5 + v6 * v6 + v7 * v7;
    sq += __shfl_xor(sq, 1);
    sq += __shfl_xor(sq, 2);
    sq += __shfl_xor(sq, 4);
    sq += __shfl_xor(sq, 8);
    sq += __shfl_xor(sq, 16);
    sq += __shfl_xor(sq, 32);
    float sc = rsqrtf(fmaxf(sq, 1e-24f));   // == 1/max(sqrt(sq),1e-12)

    // non-temporal out stores (clang ext-vector type, not HIP float4 struct)
    float* op = out + (size_t)w * D;
    f32x4 o0 = {v0 * sc, v1 * sc, v2 * sc, v3 * sc};
    __builtin_nontemporal_store(o0, (f32x4*)(op + 4 * lane));
    if (wr2) {
        f32x4 o1 = {v4 * sc, v5 * sc, v6 * sc, v7 * sc};
        __builtin_nontemporal_store(o1, (f32x4*)(op + 256 + 4 * lane));
    }
}

// ---------------- host launch ----------------
extern "C" void kernel_launch(void* const* d_in, const int* in_sizes, int n_in,
                              void* d_out, int out_size, void* d_ws, size_t ws_size,
                              hipStream_t stream) {
    const float* x  = (const float*)d_in[0];
    const int*   ei = (const int*)d_in[1];
    const float* W  = (const float*)d_in[2];
    const float* b  = (const float*)d_in[3];
    float* out = (float*)d_out;
    int n = in_sizes[0] / D;
    int e = in_sizes[1] / 2;

    char* p = (char*)d_ws;
    unsigned short* zb = (unsigned short*)p; p += (size_t)n * JP * 2;
    int* deg = (int*)p;         p += (size_t)n * 4;
    int* cursor = (int*)p;      p += (size_t)n * 4;   // adjacent to deg for one memset
    float* dinv = (float*)p;    p += (size_t)n * 4;
    int* starts = (int*)p;      p += (size_t)n * 4;
    p = (char*)(((uintptr_t)p + 15) & ~(uintptr_t)15);
    uint2* edges = (uint2*)p;   p += (size_t)e * 8;
    int* bsum = (int*)p;        p += 256 * 4;
    int* bexc = (int*)p;        p += 256 * 4;
    p = (char*)(((uintptr_t)p + 15) & ~(uintptr_t)15);
    unsigned short* wbp = (unsigned short*)p; p += (size_t)JP * KP * 2;

    int nb = (n + 1023) / 1024;

    (void)hipMemsetAsync(deg, 0, (size_t)n * 8, stream);   // deg + cursor
    k_count<<<(e + 255) / 256, 256, 0, stream>>>(ei + e, deg, e);
    k_scanA<<<nb, 256, 0, stream>>>(deg, starts, dinv, bsum, n);
    k_scanB<<<1, 256, 0, stream>>>(bsum, bexc, nb);
    k_scanC<<<(n + 255) / 256, 256, 0, stream>>>(starts, bexc, n);
    k_fill <<<(e + 255) / 256, 256, 0, stream>>>(ei, dinv, starts, cursor, edges, e);
    k_twb  <<<(JP * KP + 255) / 256, 256, 0, stream>>>(W, wbp);
    k_zmm  <<<(n + 63) / 64, 256, 0, stream>>>(x, wbp, zb, n);
    k_zgather<<<(n + 3) / 4, 256, 0, stream>>>((const uint2*)zb, edges, starts, deg,
                                               dinv, b, out, n);
}

// Round 11
// 238.092 us; speedup vs baseline: 1.2429x; 1.1633x over previous
//
#include <hip/hip_runtime.h>
#include <hip/hip_bf16.h>
#include <stdint.h>

#define D 300
#define KP 320   // K padded to 10*32 (MFMA k-loop extent)
#define JP 304   // out-col padded to 19*16; also zb row stride
#define NT 19    // col tiles (16 wide) per wave

typedef __hip_bfloat16 bf16;
typedef __bf16 bf16x8 __attribute__((ext_vector_type(8)));
typedef unsigned short us8 __attribute__((ext_vector_type(8)));
typedef float f32x4 __attribute__((ext_vector_type(4)));

static __device__ __forceinline__ unsigned short f2bu(float f) {
    bf16 h = __float2bfloat16(f);
    return *reinterpret_cast<unsigned short*>(&h);
}
static __device__ __forceinline__ float bulo(unsigned int u) {
    return __uint_as_float(u << 16);
}
static __device__ __forceinline__ float buhi(unsigned int u) {
    return __uint_as_float(u & 0xffff0000u);
}
static __device__ __forceinline__ void gload_lds16(const void* g, void* l) {
    __builtin_amdgcn_global_load_lds(
        (const __attribute__((address_space(1))) unsigned int*)g,
        (__attribute__((address_space(3))) unsigned int*)l, 16, 0, 0);
}

// ---------------- count in-degree (deg pre-zeroed by memset) ----------------
__global__ void k_count(const int* __restrict__ col, int* __restrict__ deg, int e) {
    int i = blockIdx.x * 256 + threadIdx.x;
    if (i < e) atomicAdd(&deg[col[i]], 1);
}

// ------- exclusive scan of deg (=in-degree) + fused dinv = rsqrt(deg+1) -------
__global__ void k_scanA(const int* __restrict__ deg, int* __restrict__ ex,
                        float* __restrict__ dinv, int* __restrict__ bsum, int n) {
    __shared__ int sh[256];
    int tid = threadIdx.x;
    int base = blockIdx.x * 1024 + tid * 4;
    int v[4]; int s = 0;
#pragma unroll
    for (int t = 0; t < 4; t++) {
        int i = base + t;
        v[t] = (i < n) ? deg[i] : 0;
        if (i < n) dinv[i] = rsqrtf((float)(v[t] + 1));   // +1 = self loop
        s += v[t];
    }
    sh[tid] = s;
    __syncthreads();
    for (int off = 1; off < 256; off <<= 1) {
        int t = (tid >= off) ? sh[tid - off] : 0;
        __syncthreads();
        sh[tid] += t;
        __syncthreads();
    }
    int excl = sh[tid] - s;
#pragma unroll
    for (int t = 0; t < 4; t++) {
        int i = base + t;
        if (i < n) ex[i] = excl;
        excl += v[t];
    }
    if (tid == 255) bsum[blockIdx.x] = sh[255];
}

__global__ void k_scanB(const int* __restrict__ bsum, int* __restrict__ bexc, int nb) {
    __shared__ int sh[256];
    int tid = threadIdx.x;
    int s = (tid < nb) ? bsum[tid] : 0;
    sh[tid] = s;
    __syncthreads();
    for (int off = 1; off < 256; off <<= 1) {
        int t = (tid >= off) ? sh[tid - off] : 0;
        __syncthreads();
        sh[tid] += t;
        __syncthreads();
    }
    bexc[tid] = sh[tid] - s;
}

__global__ void k_scanC(int* __restrict__ starts, const int* __restrict__ bexc, int n) {
    int i = blockIdx.x * 256 + threadIdx.x;
    if (i < n) starts[i] += bexc[i >> 10];
}

// ---------------- CSR fill (by destination), packed (src,weight) ----------------
__global__ void k_fill(const int* __restrict__ ei, const float* __restrict__ dinv,
                       const int* __restrict__ starts, int* __restrict__ cursor,
                       uint2* __restrict__ edges, int e) {
    int i = blockIdx.x * 256 + threadIdx.x;
    if (i < e) {
        int r = ei[i];          // source
        int c = ei[e + i];      // destination (aggregation index)
        int p = atomicAdd(&cursor[c], 1);
        edges[starts[c] + p] = make_uint2((unsigned int)r,
                                          __float_as_uint(dinv[r] * dinv[c]));
    }
}

// ---- W -> bf16, LDS-image layout: [kk:10][t:19][kg:4][lrow:16][8], zero-padded ----
// short index = (kk*19+t)*512 + kg*128 + lrow*8 + i; holds W[t*16+lrow][kk*32+kg*8+i]
__global__ void k_twb(const float* __restrict__ W, unsigned short* __restrict__ wbp) {
    int idx = blockIdx.x * 256 + threadIdx.x;
    if (idx < JP * KP) {
        int i = idx & 7;
        int lrow = (idx >> 3) & 15;
        int kg = (idx >> 7) & 3;
        int q = idx >> 9;             // kk*19 + t
        int kk = q / 19, t = q - kk * 19;
        int j = t * 16 + lrow;
        int k = kk * 32 + kg * 8 + i;
        wbp[idx] = (j < D && k < D) ? f2bu(W[j * D + k]) : (unsigned short)0;
    }
}

// ------ z = x @ W^T: MFMA. W: dbuf LDS (conflict-free layout, coalesced gload_lds,
//        1 barrier/k-step). A: direct per-lane fp32 loads -> bf16, 1-step prefetch.
//        block = 4 waves x 16 rows = 64 rows; wave = 16 rows x 304 cols.
__global__ __launch_bounds__(256)
void k_zmm(const float* __restrict__ x, const unsigned short* __restrict__ wbp,
           unsigned short* __restrict__ zb, int n) {
    __shared__ unsigned short Wsh[2][JP * 32];   // 2 x 19456 B
    int tid = threadIdx.x;
    int lane = tid & 63, wid = tid >> 6;
    int r0 = blockIdx.x * 64 + wid * 16;
    int lrow = lane & 15, kg = lane >> 4;

    // ---- W staging: wave wid stages 1KB slots i = wid+4j; global == LDS image ----
    int soff[5];
#pragma unroll
    for (int j = 0; j < 5; j++) {
        int i = wid + 4 * j;
        soff[j] = (i < 19) ? (i * 1024 + lane * 16) : -1;
    }
    const char* wb = (const char*)wbp;

    // ---- A: lane (kg,lrow) owns row r0+lrow, k-chunk kg*8 within each 32-k step ----
    int arow = r0 + lrow; if (arow >= n) arow = n - 1;
    const float* xr = x + (size_t)arow * D;

    f32x4 acc[NT];
#pragma unroll
    for (int t = 0; t < NT; t++) acc[t] = f32x4{0.f, 0.f, 0.f, 0.f};

    // ---- prologue: A(0) loads first, then W chunk 0 staging ----
    float4 pa, pb;
    {
        int c = kg * 8;                       // kk = 0: always in-bounds
        pa = *(const float4*)(xr + c);
        pb = *(const float4*)(xr + c + 4);
#pragma unroll
        for (int j = 0; j < 5; j++)
            if (soff[j] >= 0) gload_lds16(wb + soff[j], (char*)&Wsh[0][0] + soff[j]);
    }
    __syncthreads();   // drains A(0) + W(0)

    for (int kk = 0; kk < KP / 32; kk++) {
        float4 na, nb2;
        if (kk < KP / 32 - 1) {
            // A(kk+1) loads first (so any mid-step waits don't drain them late)
            int c = (kk + 1) * 32 + kg * 8;
            int clo = (c <= 296) ? c : 0;       // k>=300 lanes multiply zero W cols
            int chi = (c <= 292) ? c + 4 : 0;
            na  = *(const float4*)(xr + clo);
            nb2 = *(const float4*)(xr + chi);
            // W(kk+1) staging into the other buffer
            int gof = (kk + 1) * (JP * 64);     // 19456 B per chunk
            char* lbase = (char*)&Wsh[(kk + 1) & 1][0];
#pragma unroll
            for (int j = 0; j < 5; j++)
                if (soff[j] >= 0) gload_lds16(wb + gof + soff[j], lbase + soff[j]);
        }
        // compute with regs (pa,pb) + Wsh[kk&1] (ready via previous barrier)
        us8 au;
        au[0] = f2bu(pa.x); au[1] = f2bu(pa.y); au[2] = f2bu(pa.z); au[3] = f2bu(pa.w);
        au[4] = f2bu(pb.x); au[5] = f2bu(pb.y); au[6] = f2bu(pb.z); au[7] = f2bu(pb.w);
        bf16x8 av = __builtin_bit_cast(bf16x8, au);
        const unsigned short* bbase = &Wsh[kk & 1][0] + lane * 8;   // + t*512 shorts
#pragma unroll
        for (int t = 0; t < NT; t++) {
            bf16x8 bv = __builtin_bit_cast(bf16x8, *(const us8*)(bbase + t * 512));
            acc[t] = __builtin_amdgcn_mfma_f32_16x16x32_bf16(av, bv, acc[t], 0, 0, 0);
        }
        __syncthreads();   // reads of buf[kk&1] done; A(kk+1)+W(kk+1) drained
        pa = na; pb = nb2;
    }

    // ---- store z rows (bf16; cols 300..303 are zeros via zero W cols) ----
#pragma unroll
    for (int r = 0; r < 4; r++) {
        int g0 = r0 + kg * 4 + r;          // C/D: row=(lane>>4)*4+reg
        if (g0 < n) {
            unsigned short* zp0 = zb + (size_t)g0 * JP;
#pragma unroll
            for (int t = 0; t < NT; t++) {
                int j = t * 16 + lrow;
                zp0[j] = f2bu(acc[t][r]);
            }
        }
    }
}

// ------ gather on z + fused epilogue: self-loop, bias, relu, L2-norm, fp32 out ------
// z row = 76 uint2 (304 bf16). lane covers uint2 slots {lane} + {64+lane if lane<12}.
__global__ void k_zgather(const uint2* __restrict__ zb2, const uint2* __restrict__ edges,
                          const int* __restrict__ starts, const int* __restrict__ deg,
                          const float* __restrict__ dinv, const float* __restrict__ bias,
                          float* __restrict__ out, int n) {
    int w = (blockIdx.x * blockDim.x + threadIdx.x) >> 6;
    if (w >= n) return;
    int lane = threadIdx.x & 63;
    int s = starts[w];
    int cnt = deg[w];             // in-degree (edges only)
    float dc = dinv[w];
    const bool p2 = lane < 12;    // slots 64..75
    float a0 = 0.f, a1 = 0.f, a2 = 0.f, a3 = 0.f;
    float a4 = 0.f, a5 = 0.f, a6 = 0.f, a7 = 0.f;
    const uint2 Z = make_uint2(0u, 0u);

#define GACC(ua, ub, wgt)                                                     \
    {                                                                         \
        a0 += (wgt) * bulo((ua).x); a1 += (wgt) * buhi((ua).x);               \
        a2 += (wgt) * bulo((ua).y); a3 += (wgt) * buhi((ua).y);               \
        a4 += (wgt) * bulo((ub).x); a5 += (wgt) * buhi((ub).x);               \
        a6 += (wgt) * bulo((ub).y); a7 += (wgt) * buhi((ub).y);               \
    }

    int t = 0;
    for (; t + 4 <= cnt; t += 4) {
        uint2 e0 = edges[s + t],     e1 = edges[s + t + 1];
        uint2 e2 = edges[s + t + 2], e3 = edges[s + t + 3];
        const uint2* q0 = zb2 + (size_t)e0.x * 76 + lane;
        const uint2* q1 = zb2 + (size_t)e1.x * 76 + lane;
        const uint2* q2 = zb2 + (size_t)e2.x * 76 + lane;
        const uint2* q3 = zb2 + (size_t)e3.x * 76 + lane;
        uint2 u0a = q0[0], u1a = q1[0], u2a = q2[0], u3a = q3[0];
        uint2 u0b = p2 ? q0[64] : Z;
        uint2 u1b = p2 ? q1[64] : Z;
        uint2 u2b = p2 ? q2[64] : Z;
        uint2 u3b = p2 ? q3[64] : Z;
        float w0 = __uint_as_float(e0.y), w1 = __uint_as_float(e1.y);
        float w2 = __uint_as_float(e2.y), w3 = __uint_as_float(e3.y);
        GACC(u0a, u0b, w0);
        GACC(u1a, u1b, w1);
        GACC(u2a, u2b, w2);
        GACC(u3a, u3b, w3);
    }
    for (; t < cnt; t++) {
        uint2 ed = edges[s + t];
        float wg = __uint_as_float(ed.y);
        const uint2* q = zb2 + (size_t)ed.x * 76 + lane;
        uint2 ua = q[0];
        uint2 ub = p2 ? q[64] : Z;
        GACC(ua, ub, wg);
    }
    {
        float sw = dc * dc;   // self loop
        const uint2* q = zb2 + (size_t)w * 76 + lane;
        uint2 ua = q[0];
        uint2 ub = p2 ? q[64] : Z;
        GACC(ua, ub, sw);
    }
#undef GACC

    // bias + relu
    float4 b0 = *(const float4*)(bias + 4 * lane);        // dims 4l..4l+3 (<256)
    float4 b1 = {0.f, 0.f, 0.f, 0.f};
    const bool wr2 = lane < 11;                           // dims 256..299
    if (wr2) b1 = *(const float4*)(bias + 256 + 4 * lane);
    float v0 = fmaxf(a0 + b0.x, 0.f), v1 = fmaxf(a1 + b0.y, 0.f);
    float v2 = fmaxf(a2 + b0.z, 0.f), v3 = fmaxf(a3 + b0.w, 0.f);
    float v4 = fmaxf(a4 + b1.x, 0.f), v5 = fmaxf(a5 + b1.y, 0.f);
    float v6 = fmaxf(a6 + b1.z, 0.f), v7 = fmaxf(a7 + b1.w, 0.f);
    float sq = v0 * v0 + v1 * v1 + v2 * v2 + v3 * v3
             + v4 * v4 + v5 * v5 + v6 * v6 + v7 * v7;
    sq += __shfl_xor(sq, 1);
    sq += __shfl_xor(sq, 2);
    sq += __shfl_xor(sq, 4);
    sq += __shfl_xor(sq, 8);
    sq += __shfl_xor(sq, 16);
    sq += __shfl_xor(sq, 32);
    float sc = rsqrtf(fmaxf(sq, 1e-24f));   // == 1/max(sqrt(sq),1e-12)

    // non-temporal out stores (clang ext-vector type, not HIP float4 struct)
    float* op = out + (size_t)w * D;
    f32x4 o0 = {v0 * sc, v1 * sc, v2 * sc, v3 * sc};
    __builtin_nontemporal_store(o0, (f32x4*)(op + 4 * lane));
    if (wr2) {
        f32x4 o1 = {v4 * sc, v5 * sc, v6 * sc, v7 * sc};
        __builtin_nontemporal_store(o1, (f32x4*)(op + 256 + 4 * lane));
    }
}

// ---------------- host launch ----------------
extern "C" void kernel_launch(void* const* d_in, const int* in_sizes, int n_in,
                              void* d_out, int out_size, void* d_ws, size_t ws_size,
                              hipStream_t stream) {
    const float* x  = (const float*)d_in[0];
    const int*   ei = (const int*)d_in[1];
    const float* W  = (const float*)d_in[2];
    const float* b  = (const float*)d_in[3];
    float* out = (float*)d_out;
    int n = in_sizes[0] / D;
    int e = in_sizes[1] / 2;

    char* p = (char*)d_ws;
    unsigned short* zb = (unsigned short*)p; p += (size_t)n * JP * 2;
    int* deg = (int*)p;         p += (size_t)n * 4;
    int* cursor = (int*)p;      p += (size_t)n * 4;   // adjacent to deg for one memset
    float* dinv = (float*)p;    p += (size_t)n * 4;
    int* starts = (int*)p;      p += (size_t)n * 4;
    p = (char*)(((uintptr_t)p + 15) & ~(uintptr_t)15);
    uint2* edges = (uint2*)p;   p += (size_t)e * 8;
    int* bsum = (int*)p;        p += 256 * 4;
    int* bexc = (int*)p;        p += 256 * 4;
    p = (char*)(((uintptr_t)p + 15) & ~(uintptr_t)15);
    unsigned short* wbp = (unsigned short*)p; p += (size_t)JP * KP * 2;

    int nb = (n + 1023) / 1024;

    (void)hipMemsetAsync(deg, 0, (size_t)n * 8, stream);   // deg + cursor
    k_count<<<(e + 255) / 256, 256, 0, stream>>>(ei + e, deg, e);
    k_scanA<<<nb, 256, 0, stream>>>(deg, starts, dinv, bsum, n);
    k_scanB<<<1, 256, 0, stream>>>(bsum, bexc, nb);
    k_scanC<<<(n + 255) / 256, 256, 0, stream>>>(starts, bexc, n);
    k_fill <<<(e + 255) / 256, 256, 0, stream>>>(ei, dinv, starts, cursor, edges, e);
    k_twb  <<<(JP * KP + 255) / 256, 256, 0, stream>>>(W, wbp);
    k_zmm  <<<(n + 63) / 64, 256, 0, stream>>>(x, wbp, zb, n);
    k_zgather<<<(n + 3) / 4, 256, 0, stream>>>((const uint2*)zb, edges, starts, deg,
                                               dinv, b, out, n);
}